// Round 8
// baseline (207.450 us; speedup 1.0000x reference)
//
#include <hip/hip_runtime.h>
#include <math.h>

#define CDIM 128
#define HEADS 4
#define NEG 0.2f

typedef __attribute__((ext_vector_type(8))) short bf16x8;
typedef __attribute__((ext_vector_type(8))) unsigned short u16x8;
typedef __attribute__((ext_vector_type(4))) float f32x4;

static __device__ __forceinline__ unsigned short f2bf(float f) {
    unsigned u = __float_as_uint(f);
    u += 0x7FFFu + ((u >> 16) & 1u);   // round-to-nearest-even
    return (unsigned short)(u >> 16);
}
static __device__ __forceinline__ float bf2f(unsigned short s) {
    return __uint_as_float((unsigned)s << 16);
}

#define LDS_STRIDE 136   // 128 + 8 bf16 pad

// ---------------- MFMA GEMM + fused attention logits + bf16 output ----------------
__global__ __launch_bounds__(256) void gemm_mfma_kernel(const float* __restrict__ x,
                                                        const float* __restrict__ W,
                                                        const float* __restrict__ att_src,
                                                        const float* __restrict__ att_dst,
                                                        unsigned short* __restrict__ xlh,
                                                        float* __restrict__ a_src,
                                                        float* __restrict__ a_dst, int N) {
    __shared__ unsigned short As[64 * LDS_STRIDE];
    __shared__ unsigned short Bs[128 * LDS_STRIDE];
    const int tid = threadIdx.x;
    const int row0 = blockIdx.x * 64;

#pragma unroll
    for (int i = 0; i < 8; ++i) {
        int f = tid + i * 256;
        int r = f >> 5, k4 = f & 31;
        float4 v = make_float4(0.f, 0.f, 0.f, 0.f);
        int gr = row0 + r;
        if (gr < N) v = *(const float4*)(x + (size_t)gr * CDIM + k4 * 4);
        ushort4 h;
        h.x = f2bf(v.x); h.y = f2bf(v.y); h.z = f2bf(v.z); h.w = f2bf(v.w);
        *(ushort4*)(&As[r * LDS_STRIDE + k4 * 4]) = h;
    }
#pragma unroll
    for (int i = 0; i < 16; ++i) {
        int f = tid + i * 256;
        int k = f >> 5, c4 = (f & 31) * 4;
        float4 v = *(const float4*)(W + (size_t)k * CDIM + c4);
        Bs[(c4 + 0) * LDS_STRIDE + k] = f2bf(v.x);
        Bs[(c4 + 1) * LDS_STRIDE + k] = f2bf(v.y);
        Bs[(c4 + 2) * LDS_STRIDE + k] = f2bf(v.z);
        Bs[(c4 + 3) * LDS_STRIDE + k] = f2bf(v.w);
    }
    __syncthreads();

    const int wave = tid >> 6;
    const int lane = tid & 63;
    const int m    = lane & 15;
    const int quad = lane >> 4;
    const int wrow = wave * 16;

    bf16x8 a[4];
#pragma unroll
    for (int ks = 0; ks < 4; ++ks)
        a[ks] = *(const bf16x8*)(&As[(wrow + m) * LDS_STRIDE + ks * 32 + quad * 8]);

    f32x4 acc[8];
#pragma unroll
    for (int t = 0; t < 8; ++t) {
        f32x4 c = {0.f, 0.f, 0.f, 0.f};
#pragma unroll
        for (int ks = 0; ks < 4; ++ks) {
            bf16x8 b = *(const bf16x8*)(&Bs[(t * 16 + m) * LDS_STRIDE + ks * 32 + quad * 8]);
            c = __builtin_amdgcn_mfma_f32_16x16x32_bf16(a[ks], b, c, 0, 0, 0);
        }
        acc[t] = c;
    }

#pragma unroll
    for (int t = 0; t < 8; ++t) {
#pragma unroll
        for (int reg = 0; reg < 4; ++reg) {
            int row = row0 + wrow + quad * 4 + reg;
            if (row < N) xlh[(size_t)row * CDIM + t * 16 + m] = f2bf(acc[t][reg]);
        }
    }

    float ps[4][4], pd[4][4];
#pragma unroll
    for (int h = 0; h < 4; ++h)
#pragma unroll
        for (int reg = 0; reg < 4; ++reg) { ps[h][reg] = 0.f; pd[h][reg] = 0.f; }
#pragma unroll
    for (int t = 0; t < 8; ++t) {
        int h = t >> 1;
        float vs = att_src[t * 16 + m];
        float vd = att_dst[t * 16 + m];
#pragma unroll
        for (int reg = 0; reg < 4; ++reg) {
            ps[h][reg] += acc[t][reg] * vs;
            pd[h][reg] += acc[t][reg] * vd;
        }
    }
#pragma unroll
    for (int off = 8; off > 0; off >>= 1) {
#pragma unroll
        for (int h = 0; h < 4; ++h)
#pragma unroll
            for (int reg = 0; reg < 4; ++reg) {
                ps[h][reg] += __shfl_down(ps[h][reg], off, 16);
                pd[h][reg] += __shfl_down(pd[h][reg], off, 16);
            }
    }
    if (m == 0) {
#pragma unroll
        for (int reg = 0; reg < 4; ++reg) {
            int row = row0 + wrow + quad * 4 + reg;
            if (row < N) {
#pragma unroll
                for (int h = 0; h < 4; ++h) {
                    a_src[row * 4 + h] = ps[h][reg];
                    a_dst[row * 4 + h] = pd[h][reg];
                }
            }
        }
    }
}

// ---------------- CSR build: histogram + per-edge rank ----------------
__global__ __launch_bounds__(256) void hist_kernel(const int* __restrict__ src,
                                                   const int* __restrict__ dst,
                                                   int* __restrict__ counts,
                                                   int* __restrict__ rank, int E) {
    int e = blockIdx.x * 256 + threadIdx.x;
    if (e >= E) return;
    int s = src[e], d = dst[e];
    if (s != d) rank[e] = atomicAdd(&counts[d], 1);
}

__global__ __launch_bounds__(256) void reduce_kernel(const int* __restrict__ counts,
                                                     int* __restrict__ blockSums, int N) {
    __shared__ int sh[256];
    int idx = blockIdx.x * 256 + threadIdx.x;
    sh[threadIdx.x] = (idx < N) ? counts[idx] : 0;
    __syncthreads();
    for (int off = 128; off > 0; off >>= 1) {
        if (threadIdx.x < off) sh[threadIdx.x] += sh[threadIdx.x + off];
        __syncthreads();
    }
    if (threadIdx.x == 0) blockSums[blockIdx.x] = sh[0];
}

__global__ __launch_bounds__(256) void scan_top_kernel(int* __restrict__ blockSums,
                                                       int* __restrict__ blockPrefix, int nb) {
    __shared__ int sh[256];
    int t = threadIdx.x;
    sh[t] = (t < nb) ? blockSums[t] : 0;
    __syncthreads();
    for (int off = 1; off < 256; off <<= 1) {
        int v = (t >= off) ? sh[t - off] : 0;
        __syncthreads();
        sh[t] += v;
        __syncthreads();
    }
    if (t < nb) blockPrefix[t] = (t == 0) ? 0 : sh[t - 1];
}

__global__ __launch_bounds__(256) void apply_kernel(const int* __restrict__ counts,
                                                    const int* __restrict__ blockPrefix,
                                                    int* __restrict__ offsets, int N) {
    __shared__ int sh[256];
    int idx = blockIdx.x * 256 + threadIdx.x;
    int t = threadIdx.x;
    int c = (idx < N) ? counts[idx] : 0;
    sh[t] = c;
    __syncthreads();
    for (int off = 1; off < 256; off <<= 1) {
        int v = (t >= off) ? sh[t - off] : 0;
        __syncthreads();
        sh[t] += v;
        __syncthreads();
    }
    if (idx < N) offsets[idx] = sh[t] - c + blockPrefix[blockIdx.x];
}

// pure scatter: no atomics
__global__ __launch_bounds__(256) void scatter_kernel(const int* __restrict__ src,
                                                      const int* __restrict__ dst,
                                                      const int* __restrict__ offsets,
                                                      const int* __restrict__ rank,
                                                      int* __restrict__ bucket, int E) {
    int e = blockIdx.x * 256 + threadIdx.x;
    if (e >= E) return;
    int s = src[e], d = dst[e];
    if (s == d) return;
    bucket[offsets[d] + rank[e]] = s;
}

// ---------------- gather v3: 16 lanes/node (ushort8), 4 consecutive nodes per group ----------------
#define GNODES 4
__global__ __launch_bounds__(256) void gather_kernel(const int* __restrict__ offsets,
                                                     const int* __restrict__ counts,
                                                     const int* __restrict__ bucket,
                                                     const unsigned short* __restrict__ xlh,
                                                     const float* __restrict__ a_src,
                                                     const float* __restrict__ a_dst,
                                                     const float* __restrict__ bias,
                                                     float* __restrict__ out, int N) {
    const int group = threadIdx.x >> 4;           // 0..15
    const int lane16 = threadIdx.x & 15;
    const int gid = blockIdx.x * 16 + group;
    int node0 = gid * GNODES;
    if (node0 >= N) return;
    const int c8 = lane16 * 8;                    // 8 channels per lane
    const int h = lane16 >> 2;                    // head (4 lanes per head)

    // hoisted bias for this lane's channels
    float4 b0 = *(const float4*)(bias + c8);
    float4 b1 = *(const float4*)(bias + c8 + 4);

    int nodeEnd = node0 + GNODES;
    if (nodeEnd > N) nodeEnd = N;

    for (int node = node0; node < nodeEnd; ++node) {
        const float ad = a_dst[node * 4 + h];
        const int beg = offsets[node];
        const int cnt = counts[node];

        float acc[8];
#pragma unroll
        for (int i = 0; i < 8; ++i) acc[i] = 0.f;
        float den = 0.f;

        int j = 0;
        for (; j + 4 <= cnt; j += 4) {
            int s0 = bucket[beg + j + 0];
            int s1 = bucket[beg + j + 1];
            int s2 = bucket[beg + j + 2];
            int s3 = bucket[beg + j + 3];
            float e0 = a_src[s0 * 4 + h] + ad;
            float e1 = a_src[s1 * 4 + h] + ad;
            float e2 = a_src[s2 * 4 + h] + ad;
            float e3 = a_src[s3 * 4 + h] + ad;
            u16x8 u0 = *(const u16x8*)(xlh + (size_t)s0 * CDIM + c8);
            u16x8 u1 = *(const u16x8*)(xlh + (size_t)s1 * CDIM + c8);
            u16x8 u2 = *(const u16x8*)(xlh + (size_t)s2 * CDIM + c8);
            u16x8 u3 = *(const u16x8*)(xlh + (size_t)s3 * CDIM + c8);
            e0 = e0 > 0.f ? e0 : NEG * e0;
            e1 = e1 > 0.f ? e1 : NEG * e1;
            e2 = e2 > 0.f ? e2 : NEG * e2;
            e3 = e3 > 0.f ? e3 : NEG * e3;
            float w0 = __expf(e0), w1 = __expf(e1), w2 = __expf(e2), w3 = __expf(e3);
#pragma unroll
            for (int i = 0; i < 8; ++i) {
                acc[i] += w0 * bf2f(u0[i]) + w1 * bf2f(u1[i])
                        + w2 * bf2f(u2[i]) + w3 * bf2f(u3[i]);
            }
            den += w0 + w1 + w2 + w3;
        }
        for (; j < cnt; ++j) {
            int s = bucket[beg + j];
            float e = a_src[s * 4 + h] + ad;
            u16x8 u = *(const u16x8*)(xlh + (size_t)s * CDIM + c8);
            e = e > 0.f ? e : NEG * e;
            float w = __expf(e);
#pragma unroll
            for (int i = 0; i < 8; ++i) acc[i] += w * bf2f(u[i]);
            den += w;
        }
        // self loop
        float es = a_src[node * 4 + h] + ad;
        es = es > 0.f ? es : NEG * es;
        float ws = __expf(es);
        u16x8 u = *(const u16x8*)(xlh + (size_t)node * CDIM + c8);
#pragma unroll
        for (int i = 0; i < 8; ++i) acc[i] += ws * bf2f(u[i]);
        den += ws;

        float inv = 1.0f / den;
        float4 o0, o1;
        o0.x = (acc[0] * inv + b0.x) * 0.5f;
        o0.y = (acc[1] * inv + b0.y) * 0.5f;
        o0.z = (acc[2] * inv + b0.z) * 0.5f;
        o0.w = (acc[3] * inv + b0.w) * 0.5f;
        o1.x = (acc[4] * inv + b1.x) * 0.5f;
        o1.y = (acc[5] * inv + b1.y) * 0.5f;
        o1.z = (acc[6] * inv + b1.z) * 0.5f;
        o1.w = (acc[7] * inv + b1.w) * 0.5f;
        *(float4*)(out + (size_t)node * CDIM + c8) = o0;
        *(float4*)(out + (size_t)node * CDIM + c8 + 4) = o1;
    }
}

extern "C" void kernel_launch(void* const* d_in, const int* in_sizes, int n_in,
                              void* d_out, int out_size, void* d_ws, size_t ws_size,
                              hipStream_t stream) {
    const float* x       = (const float*)d_in[0];
    const int*   ei      = (const int*)d_in[1];
    const float* W       = (const float*)d_in[2];
    const float* att_src = (const float*)d_in[3];
    const float* att_dst = (const float*)d_in[4];
    const float* bias    = (const float*)d_in[5];
    float* out = (float*)d_out;

    const int N = in_sizes[0] / CDIM;
    const int E = in_sizes[1] / 2;
    const int nb = (N + 255) / 256;

    char* wsb = (char*)d_ws;
    unsigned short* xlh = (unsigned short*)wsb;         wsb += (size_t)N * CDIM * sizeof(unsigned short);
    float* a_src = (float*)wsb;                         wsb += (size_t)N * HEADS * sizeof(float);
    float* a_dst = (float*)wsb;                         wsb += (size_t)N * HEADS * sizeof(float);
    int* counts  = (int*)wsb;                           wsb += (size_t)N * sizeof(int);
    int* offsets = (int*)wsb;                           wsb += (size_t)N * sizeof(int);
    int* blockSums   = (int*)wsb;                       wsb += (size_t)nb * sizeof(int);
    int* blockPrefix = (int*)wsb;                       wsb += (size_t)nb * sizeof(int);
    int* rank    = (int*)wsb;                           wsb += (size_t)E * sizeof(int);
    int* bucket  = (int*)wsb;                           wsb += (size_t)E * sizeof(int);

    hipMemsetAsync(counts, 0, (size_t)N * sizeof(int), stream);

    gemm_mfma_kernel<<<(N + 63) / 64, 256, 0, stream>>>(x, W, att_src, att_dst, xlh, a_src, a_dst, N);
    hist_kernel<<<(E + 255) / 256, 256, 0, stream>>>(ei, ei + E, counts, rank, E);
    reduce_kernel<<<nb, 256, 0, stream>>>(counts, blockSums, N);
    scan_top_kernel<<<1, 256, 0, stream>>>(blockSums, blockPrefix, nb);
    apply_kernel<<<nb, 256, 0, stream>>>(counts, blockPrefix, offsets, N);
    scatter_kernel<<<(E + 255) / 256, 256, 0, stream>>>(ei, ei + E, offsets, rank, bucket, E);
    int ngroups = (N + GNODES - 1) / GNODES;
    gather_kernel<<<(ngroups + 15) / 16, 256, 0, stream>>>(offsets, counts, bucket, xlh, a_src, a_dst, bias, out, N);
}

// Round 9
// 201.741 us; speedup vs baseline: 1.0283x; 1.0283x over previous
//
#include <hip/hip_runtime.h>
#include <math.h>

#define CDIM 128
#define HEADS 4
#define NEG 0.2f

typedef __attribute__((ext_vector_type(8))) short bf16x8;
typedef __attribute__((ext_vector_type(8))) unsigned short u16x8;
typedef __attribute__((ext_vector_type(4))) float f32x4;

static __device__ __forceinline__ unsigned short f2bf(float f) {
    unsigned u = __float_as_uint(f);
    u += 0x7FFFu + ((u >> 16) & 1u);   // round-to-nearest-even
    return (unsigned short)(u >> 16);
}
static __device__ __forceinline__ float bf2f(unsigned short s) {
    return __uint_as_float((unsigned)s << 16);
}

#define LDS_STRIDE 136   // 128 + 8 bf16 pad

// ---------------- MFMA GEMM + fused attention logits + bf16 output ----------------
__global__ __launch_bounds__(256) void gemm_mfma_kernel(const float* __restrict__ x,
                                                        const float* __restrict__ W,
                                                        const float* __restrict__ att_src,
                                                        const float* __restrict__ att_dst,
                                                        unsigned short* __restrict__ xlh,
                                                        float* __restrict__ a_src,
                                                        float* __restrict__ a_dst, int N) {
    __shared__ unsigned short As[64 * LDS_STRIDE];
    __shared__ unsigned short Bs[128 * LDS_STRIDE];
    const int tid = threadIdx.x;
    const int row0 = blockIdx.x * 64;

#pragma unroll
    for (int i = 0; i < 8; ++i) {
        int f = tid + i * 256;
        int r = f >> 5, k4 = f & 31;
        float4 v = make_float4(0.f, 0.f, 0.f, 0.f);
        int gr = row0 + r;
        if (gr < N) v = *(const float4*)(x + (size_t)gr * CDIM + k4 * 4);
        ushort4 h;
        h.x = f2bf(v.x); h.y = f2bf(v.y); h.z = f2bf(v.z); h.w = f2bf(v.w);
        *(ushort4*)(&As[r * LDS_STRIDE + k4 * 4]) = h;
    }
#pragma unroll
    for (int i = 0; i < 16; ++i) {
        int f = tid + i * 256;
        int k = f >> 5, c4 = (f & 31) * 4;
        float4 v = *(const float4*)(W + (size_t)k * CDIM + c4);
        Bs[(c4 + 0) * LDS_STRIDE + k] = f2bf(v.x);
        Bs[(c4 + 1) * LDS_STRIDE + k] = f2bf(v.y);
        Bs[(c4 + 2) * LDS_STRIDE + k] = f2bf(v.z);
        Bs[(c4 + 3) * LDS_STRIDE + k] = f2bf(v.w);
    }
    __syncthreads();

    const int wave = tid >> 6;
    const int lane = tid & 63;
    const int m    = lane & 15;
    const int quad = lane >> 4;
    const int wrow = wave * 16;

    bf16x8 a[4];
#pragma unroll
    for (int ks = 0; ks < 4; ++ks)
        a[ks] = *(const bf16x8*)(&As[(wrow + m) * LDS_STRIDE + ks * 32 + quad * 8]);

    f32x4 acc[8];
#pragma unroll
    for (int t = 0; t < 8; ++t) {
        f32x4 c = {0.f, 0.f, 0.f, 0.f};
#pragma unroll
        for (int ks = 0; ks < 4; ++ks) {
            bf16x8 b = *(const bf16x8*)(&Bs[(t * 16 + m) * LDS_STRIDE + ks * 32 + quad * 8]);
            c = __builtin_amdgcn_mfma_f32_16x16x32_bf16(a[ks], b, c, 0, 0, 0);
        }
        acc[t] = c;
    }

#pragma unroll
    for (int t = 0; t < 8; ++t) {
#pragma unroll
        for (int reg = 0; reg < 4; ++reg) {
            int row = row0 + wrow + quad * 4 + reg;
            if (row < N) xlh[(size_t)row * CDIM + t * 16 + m] = f2bf(acc[t][reg]);
        }
    }

    float ps[4][4], pd[4][4];
#pragma unroll
    for (int h = 0; h < 4; ++h)
#pragma unroll
        for (int reg = 0; reg < 4; ++reg) { ps[h][reg] = 0.f; pd[h][reg] = 0.f; }
#pragma unroll
    for (int t = 0; t < 8; ++t) {
        int h = t >> 1;
        float vs = att_src[t * 16 + m];
        float vd = att_dst[t * 16 + m];
#pragma unroll
        for (int reg = 0; reg < 4; ++reg) {
            ps[h][reg] += acc[t][reg] * vs;
            pd[h][reg] += acc[t][reg] * vd;
        }
    }
#pragma unroll
    for (int off = 8; off > 0; off >>= 1) {
#pragma unroll
        for (int h = 0; h < 4; ++h)
#pragma unroll
            for (int reg = 0; reg < 4; ++reg) {
                ps[h][reg] += __shfl_down(ps[h][reg], off, 16);
                pd[h][reg] += __shfl_down(pd[h][reg], off, 16);
            }
    }
    if (m == 0) {
#pragma unroll
        for (int reg = 0; reg < 4; ++reg) {
            int row = row0 + wrow + quad * 4 + reg;
            if (row < N) {
#pragma unroll
                for (int h = 0; h < 4; ++h) {
                    a_src[row * 4 + h] = ps[h][reg];
                    a_dst[row * 4 + h] = pd[h][reg];
                }
            }
        }
    }
}

// ---------------- CSR build: histogram + per-edge rank ----------------
__global__ __launch_bounds__(256) void hist_kernel(const int* __restrict__ src,
                                                   const int* __restrict__ dst,
                                                   int* __restrict__ counts,
                                                   int* __restrict__ rank, int E) {
    int e = blockIdx.x * 256 + threadIdx.x;
    if (e >= E) return;
    int s = src[e], d = dst[e];
    if (s != d) rank[e] = atomicAdd(&counts[d], 1);
}

__global__ __launch_bounds__(256) void reduce_kernel(const int* __restrict__ counts,
                                                     int* __restrict__ blockSums, int N) {
    __shared__ int sh[256];
    int idx = blockIdx.x * 256 + threadIdx.x;
    sh[threadIdx.x] = (idx < N) ? counts[idx] : 0;
    __syncthreads();
    for (int off = 128; off > 0; off >>= 1) {
        if (threadIdx.x < off) sh[threadIdx.x] += sh[threadIdx.x + off];
        __syncthreads();
    }
    if (threadIdx.x == 0) blockSums[blockIdx.x] = sh[0];
}

__global__ __launch_bounds__(256) void scan_top_kernel(int* __restrict__ blockSums,
                                                       int* __restrict__ blockPrefix, int nb) {
    __shared__ int sh[256];
    int t = threadIdx.x;
    sh[t] = (t < nb) ? blockSums[t] : 0;
    __syncthreads();
    for (int off = 1; off < 256; off <<= 1) {
        int v = (t >= off) ? sh[t - off] : 0;
        __syncthreads();
        sh[t] += v;
        __syncthreads();
    }
    if (t < nb) blockPrefix[t] = (t == 0) ? 0 : sh[t - 1];
}

__global__ __launch_bounds__(256) void apply_kernel(const int* __restrict__ counts,
                                                    const int* __restrict__ blockPrefix,
                                                    int* __restrict__ offsets, int N) {
    __shared__ int sh[256];
    int idx = blockIdx.x * 256 + threadIdx.x;
    int t = threadIdx.x;
    int c = (idx < N) ? counts[idx] : 0;
    sh[t] = c;
    __syncthreads();
    for (int off = 1; off < 256; off <<= 1) {
        int v = (t >= off) ? sh[t - off] : 0;
        __syncthreads();
        sh[t] += v;
        __syncthreads();
    }
    if (idx < N) offsets[idx] = sh[t] - c + blockPrefix[blockIdx.x];
}

// pure scatter: no atomics
__global__ __launch_bounds__(256) void scatter_kernel(const int* __restrict__ src,
                                                      const int* __restrict__ dst,
                                                      const int* __restrict__ offsets,
                                                      const int* __restrict__ rank,
                                                      int* __restrict__ bucket, int E) {
    int e = blockIdx.x * 256 + threadIdx.x;
    if (e >= E) return;
    int s = src[e], d = dst[e];
    if (s == d) return;
    bucket[offsets[d] + rank[e]] = s;
}

// ---------------- gather v4: 16 lanes/node (ushort8), ONE node per group ----------------
__global__ __launch_bounds__(256) void gather_kernel(const int* __restrict__ offsets,
                                                     const int* __restrict__ counts,
                                                     const int* __restrict__ bucket,
                                                     const unsigned short* __restrict__ xlh,
                                                     const float* __restrict__ a_src,
                                                     const float* __restrict__ a_dst,
                                                     const float* __restrict__ bias,
                                                     float* __restrict__ out, int N) {
    const int node = blockIdx.x * 16 + (threadIdx.x >> 4);
    const int lane16 = threadIdx.x & 15;
    if (node >= N) return;
    const int c8 = lane16 * 8;                    // 8 channels per lane
    const int h = lane16 >> 2;                    // head (4 lanes per head)

    const float ad = a_dst[node * 4 + h];
    const int beg = offsets[node];
    const int cnt = counts[node];

    float acc[8];
#pragma unroll
    for (int i = 0; i < 8; ++i) acc[i] = 0.f;
    float den = 0.f;

    int j = 0;
    for (; j + 4 <= cnt; j += 4) {
        int s0 = bucket[beg + j + 0];
        int s1 = bucket[beg + j + 1];
        int s2 = bucket[beg + j + 2];
        int s3 = bucket[beg + j + 3];
        float e0 = a_src[s0 * 4 + h] + ad;
        float e1 = a_src[s1 * 4 + h] + ad;
        float e2 = a_src[s2 * 4 + h] + ad;
        float e3 = a_src[s3 * 4 + h] + ad;
        u16x8 u0 = *(const u16x8*)(xlh + (size_t)s0 * CDIM + c8);
        u16x8 u1 = *(const u16x8*)(xlh + (size_t)s1 * CDIM + c8);
        u16x8 u2 = *(const u16x8*)(xlh + (size_t)s2 * CDIM + c8);
        u16x8 u3 = *(const u16x8*)(xlh + (size_t)s3 * CDIM + c8);
        e0 = e0 > 0.f ? e0 : NEG * e0;
        e1 = e1 > 0.f ? e1 : NEG * e1;
        e2 = e2 > 0.f ? e2 : NEG * e2;
        e3 = e3 > 0.f ? e3 : NEG * e3;
        float w0 = __expf(e0), w1 = __expf(e1), w2 = __expf(e2), w3 = __expf(e3);
#pragma unroll
        for (int i = 0; i < 8; ++i) {
            acc[i] += w0 * bf2f(u0[i]) + w1 * bf2f(u1[i])
                    + w2 * bf2f(u2[i]) + w3 * bf2f(u3[i]);
        }
        den += w0 + w1 + w2 + w3;
    }
    for (; j < cnt; ++j) {
        int s = bucket[beg + j];
        float e = a_src[s * 4 + h] + ad;
        u16x8 u = *(const u16x8*)(xlh + (size_t)s * CDIM + c8);
        e = e > 0.f ? e : NEG * e;
        float w = __expf(e);
#pragma unroll
        for (int i = 0; i < 8; ++i) acc[i] += w * bf2f(u[i]);
        den += w;
    }
    // self loop
    float es = a_src[node * 4 + h] + ad;
    es = es > 0.f ? es : NEG * es;
    float ws = __expf(es);
    u16x8 u = *(const u16x8*)(xlh + (size_t)node * CDIM + c8);
#pragma unroll
    for (int i = 0; i < 8; ++i) acc[i] += ws * bf2f(u[i]);
    den += ws;

    float inv = 1.0f / den;
    float4 b0 = *(const float4*)(bias + c8);
    float4 b1 = *(const float4*)(bias + c8 + 4);
    float4 o0, o1;
    o0.x = (acc[0] * inv + b0.x) * 0.5f;
    o0.y = (acc[1] * inv + b0.y) * 0.5f;
    o0.z = (acc[2] * inv + b0.z) * 0.5f;
    o0.w = (acc[3] * inv + b0.w) * 0.5f;
    o1.x = (acc[4] * inv + b1.x) * 0.5f;
    o1.y = (acc[5] * inv + b1.y) * 0.5f;
    o1.z = (acc[6] * inv + b1.z) * 0.5f;
    o1.w = (acc[7] * inv + b1.w) * 0.5f;
    *(float4*)(out + (size_t)node * CDIM + c8) = o0;
    *(float4*)(out + (size_t)node * CDIM + c8 + 4) = o1;
}

extern "C" void kernel_launch(void* const* d_in, const int* in_sizes, int n_in,
                              void* d_out, int out_size, void* d_ws, size_t ws_size,
                              hipStream_t stream) {
    const float* x       = (const float*)d_in[0];
    const int*   ei      = (const int*)d_in[1];
    const float* W       = (const float*)d_in[2];
    const float* att_src = (const float*)d_in[3];
    const float* att_dst = (const float*)d_in[4];
    const float* bias    = (const float*)d_in[5];
    float* out = (float*)d_out;

    const int N = in_sizes[0] / CDIM;
    const int E = in_sizes[1] / 2;
    const int nb = (N + 255) / 256;

    char* wsb = (char*)d_ws;
    unsigned short* xlh = (unsigned short*)wsb;         wsb += (size_t)N * CDIM * sizeof(unsigned short);
    float* a_src = (float*)wsb;                         wsb += (size_t)N * HEADS * sizeof(float);
    float* a_dst = (float*)wsb;                         wsb += (size_t)N * HEADS * sizeof(float);
    int* counts  = (int*)wsb;                           wsb += (size_t)N * sizeof(int);
    int* offsets = (int*)wsb;                           wsb += (size_t)N * sizeof(int);
    int* blockSums   = (int*)wsb;                       wsb += (size_t)nb * sizeof(int);
    int* blockPrefix = (int*)wsb;                       wsb += (size_t)nb * sizeof(int);
    int* rank    = (int*)wsb;                           wsb += (size_t)E * sizeof(int);
    int* bucket  = (int*)wsb;                           wsb += (size_t)E * sizeof(int);

    hipMemsetAsync(counts, 0, (size_t)N * sizeof(int), stream);

    gemm_mfma_kernel<<<(N + 63) / 64, 256, 0, stream>>>(x, W, att_src, att_dst, xlh, a_src, a_dst, N);
    hist_kernel<<<(E + 255) / 256, 256, 0, stream>>>(ei, ei + E, counts, rank, E);
    reduce_kernel<<<nb, 256, 0, stream>>>(counts, blockSums, N);
    scan_top_kernel<<<1, 256, 0, stream>>>(blockSums, blockPrefix, nb);
    apply_kernel<<<nb, 256, 0, stream>>>(counts, blockPrefix, offsets, N);
    scatter_kernel<<<(E + 255) / 256, 256, 0, stream>>>(ei, ei + E, offsets, rank, bucket, E);
    gather_kernel<<<(N + 15) / 16, 256, 0, stream>>>(offsets, counts, bucket, xlh, a_src, a_dst, bias, out, N);
}

// Round 10
// 194.073 us; speedup vs baseline: 1.0689x; 1.0395x over previous
//
#include <hip/hip_runtime.h>
#include <math.h>

#define CDIM 128
#define HEADS 4
#define NEG 0.2f

typedef __attribute__((ext_vector_type(8))) short bf16x8;
typedef __attribute__((ext_vector_type(8))) unsigned short u16x8;
typedef __attribute__((ext_vector_type(4))) float f32x4;

static __device__ __forceinline__ unsigned short f2bf(float f) {
    unsigned u = __float_as_uint(f);
    u += 0x7FFFu + ((u >> 16) & 1u);   // round-to-nearest-even
    return (unsigned short)(u >> 16);
}
static __device__ __forceinline__ float bf2f(unsigned short s) {
    return __uint_as_float((unsigned)s << 16);
}

#define LDS_STRIDE 136   // 128 + 8 bf16 pad

// ---------------- fused: MFMA GEMM (+logits, bf16 out)  ∥  edge histogram+rank ----------------
// blocks [0, gemmBlocks): gemm on 64 rows each; blocks [gemmBlocks, +histBlocks): hist on 256 edges each.
// Independent inputs/outputs; MFMA-bound and atomic-latency-bound waves co-schedule (m114).
__global__ __launch_bounds__(256) void gemm_hist_kernel(const float* __restrict__ x,
                                                        const float* __restrict__ W,
                                                        const float* __restrict__ att_src,
                                                        const float* __restrict__ att_dst,
                                                        unsigned short* __restrict__ xlh,
                                                        float* __restrict__ a_src,
                                                        float* __restrict__ a_dst, int N,
                                                        const int* __restrict__ esrc,
                                                        const int* __restrict__ edst,
                                                        int* __restrict__ counts,
                                                        int* __restrict__ rank, int E,
                                                        int gemmBlocks) {
    __shared__ unsigned short As[64 * LDS_STRIDE];
    __shared__ unsigned short Bs[128 * LDS_STRIDE];

    if (blockIdx.x >= gemmBlocks) {
        // ---- histogram branch ----
        int e = (blockIdx.x - gemmBlocks) * 256 + threadIdx.x;
        if (e < E) {
            int s = esrc[e], d = edst[e];
            if (s != d) rank[e] = atomicAdd(&counts[d], 1);
        }
        return;
    }

    // ---- gemm branch ----
    const int tid = threadIdx.x;
    const int row0 = blockIdx.x * 64;

#pragma unroll
    for (int i = 0; i < 8; ++i) {
        int f = tid + i * 256;
        int r = f >> 5, k4 = f & 31;
        float4 v = make_float4(0.f, 0.f, 0.f, 0.f);
        int gr = row0 + r;
        if (gr < N) v = *(const float4*)(x + (size_t)gr * CDIM + k4 * 4);
        ushort4 h;
        h.x = f2bf(v.x); h.y = f2bf(v.y); h.z = f2bf(v.z); h.w = f2bf(v.w);
        *(ushort4*)(&As[r * LDS_STRIDE + k4 * 4]) = h;
    }
#pragma unroll
    for (int i = 0; i < 16; ++i) {
        int f = tid + i * 256;
        int k = f >> 5, c4 = (f & 31) * 4;
        float4 v = *(const float4*)(W + (size_t)k * CDIM + c4);
        Bs[(c4 + 0) * LDS_STRIDE + k] = f2bf(v.x);
        Bs[(c4 + 1) * LDS_STRIDE + k] = f2bf(v.y);
        Bs[(c4 + 2) * LDS_STRIDE + k] = f2bf(v.z);
        Bs[(c4 + 3) * LDS_STRIDE + k] = f2bf(v.w);
    }
    __syncthreads();

    const int wave = tid >> 6;
    const int lane = tid & 63;
    const int m    = lane & 15;
    const int quad = lane >> 4;
    const int wrow = wave * 16;

    bf16x8 a[4];
#pragma unroll
    for (int ks = 0; ks < 4; ++ks)
        a[ks] = *(const bf16x8*)(&As[(wrow + m) * LDS_STRIDE + ks * 32 + quad * 8]);

    f32x4 acc[8];
#pragma unroll
    for (int t = 0; t < 8; ++t) {
        f32x4 c = {0.f, 0.f, 0.f, 0.f};
#pragma unroll
        for (int ks = 0; ks < 4; ++ks) {
            bf16x8 b = *(const bf16x8*)(&Bs[(t * 16 + m) * LDS_STRIDE + ks * 32 + quad * 8]);
            c = __builtin_amdgcn_mfma_f32_16x16x32_bf16(a[ks], b, c, 0, 0, 0);
        }
        acc[t] = c;
    }

#pragma unroll
    for (int t = 0; t < 8; ++t) {
#pragma unroll
        for (int reg = 0; reg < 4; ++reg) {
            int row = row0 + wrow + quad * 4 + reg;
            if (row < N) xlh[(size_t)row * CDIM + t * 16 + m] = f2bf(acc[t][reg]);
        }
    }

    float ps[4][4], pd[4][4];
#pragma unroll
    for (int h = 0; h < 4; ++h)
#pragma unroll
        for (int reg = 0; reg < 4; ++reg) { ps[h][reg] = 0.f; pd[h][reg] = 0.f; }
#pragma unroll
    for (int t = 0; t < 8; ++t) {
        int h = t >> 1;
        float vs = att_src[t * 16 + m];
        float vd = att_dst[t * 16 + m];
#pragma unroll
        for (int reg = 0; reg < 4; ++reg) {
            ps[h][reg] += acc[t][reg] * vs;
            pd[h][reg] += acc[t][reg] * vd;
        }
    }
#pragma unroll
    for (int off = 8; off > 0; off >>= 1) {
#pragma unroll
        for (int h = 0; h < 4; ++h)
#pragma unroll
            for (int reg = 0; reg < 4; ++reg) {
                ps[h][reg] += __shfl_down(ps[h][reg], off, 16);
                pd[h][reg] += __shfl_down(pd[h][reg], off, 16);
            }
    }
    if (m == 0) {
#pragma unroll
        for (int reg = 0; reg < 4; ++reg) {
            int row = row0 + wrow + quad * 4 + reg;
            if (row < N) {
#pragma unroll
                for (int h = 0; h < 4; ++h) {
                    a_src[row * 4 + h] = ps[h][reg];
                    a_dst[row * 4 + h] = pd[h][reg];
                }
            }
        }
    }
}

// ---------------- single-pass scan: block-local exclusive scan + atomic block base ----------------
// Bucket bases are assigned in nondeterministic block order — any consistent CSR is valid.
__global__ __launch_bounds__(256) void scan_fused_kernel(const int* __restrict__ counts,
                                                         int* __restrict__ offsets,
                                                         int* __restrict__ cursor, int N) {
    __shared__ int sh[256];
    __shared__ int baseSh;
    int idx = blockIdx.x * 256 + threadIdx.x;
    int t = threadIdx.x;
    int c = (idx < N) ? counts[idx] : 0;
    sh[t] = c;
    __syncthreads();
    for (int off = 1; off < 256; off <<= 1) {
        int v = (t >= off) ? sh[t - off] : 0;
        __syncthreads();
        sh[t] += v;
        __syncthreads();
    }
    if (t == 255) baseSh = atomicAdd(cursor, sh[255]);
    __syncthreads();
    if (idx < N) offsets[idx] = baseSh + sh[t] - c;
}

// pure scatter: no atomics
__global__ __launch_bounds__(256) void scatter_kernel(const int* __restrict__ src,
                                                      const int* __restrict__ dst,
                                                      const int* __restrict__ offsets,
                                                      const int* __restrict__ rank,
                                                      int* __restrict__ bucket, int E) {
    int e = blockIdx.x * 256 + threadIdx.x;
    if (e >= E) return;
    int s = src[e], d = dst[e];
    if (s == d) return;
    bucket[offsets[d] + rank[e]] = s;
}

// ---------------- gather: 16 lanes/node (ushort8), one node/group, 8x unrolled ----------------
__global__ __launch_bounds__(256) void gather_kernel(const int* __restrict__ offsets,
                                                     const int* __restrict__ counts,
                                                     const int* __restrict__ bucket,
                                                     const unsigned short* __restrict__ xlh,
                                                     const float* __restrict__ a_src,
                                                     const float* __restrict__ a_dst,
                                                     const float* __restrict__ bias,
                                                     float* __restrict__ out, int N) {
    const int node = blockIdx.x * 16 + (threadIdx.x >> 4);
    const int lane16 = threadIdx.x & 15;
    if (node >= N) return;
    const int c8 = lane16 * 8;
    const int h = lane16 >> 2;

    const float ad = a_dst[node * 4 + h];
    const int beg = offsets[node];
    const int cnt = counts[node];

    float acc[8];
#pragma unroll
    for (int i = 0; i < 8; ++i) acc[i] = 0.f;
    float den = 0.f;

    int j = 0;
    for (; j + 8 <= cnt; j += 8) {
        int s[8];
#pragma unroll
        for (int q = 0; q < 8; ++q) s[q] = bucket[beg + j + q];
        float e[8];
#pragma unroll
        for (int q = 0; q < 8; ++q) e[q] = a_src[s[q] * 4 + h] + ad;
        u16x8 u[8];
#pragma unroll
        for (int q = 0; q < 8; ++q) u[q] = *(const u16x8*)(xlh + (size_t)s[q] * CDIM + c8);
        float w[8];
#pragma unroll
        for (int q = 0; q < 8; ++q) {
            float eq = e[q] > 0.f ? e[q] : NEG * e[q];
            w[q] = __expf(eq);
        }
#pragma unroll
        for (int q = 0; q < 8; ++q) {
#pragma unroll
            for (int i = 0; i < 8; ++i) acc[i] += w[q] * bf2f(u[q][i]);
            den += w[q];
        }
    }
    for (; j < cnt; ++j) {
        int s = bucket[beg + j];
        float e = a_src[s * 4 + h] + ad;
        u16x8 u = *(const u16x8*)(xlh + (size_t)s * CDIM + c8);
        e = e > 0.f ? e : NEG * e;
        float w = __expf(e);
#pragma unroll
        for (int i = 0; i < 8; ++i) acc[i] += w * bf2f(u[i]);
        den += w;
    }
    // self loop
    float es = a_src[node * 4 + h] + ad;
    es = es > 0.f ? es : NEG * es;
    float ws = __expf(es);
    u16x8 u = *(const u16x8*)(xlh + (size_t)node * CDIM + c8);
#pragma unroll
    for (int i = 0; i < 8; ++i) acc[i] += ws * bf2f(u[i]);
    den += ws;

    float inv = 1.0f / den;
    float4 b0 = *(const float4*)(bias + c8);
    float4 b1 = *(const float4*)(bias + c8 + 4);
    float4 o0, o1;
    o0.x = (acc[0] * inv + b0.x) * 0.5f;
    o0.y = (acc[1] * inv + b0.y) * 0.5f;
    o0.z = (acc[2] * inv + b0.z) * 0.5f;
    o0.w = (acc[3] * inv + b0.w) * 0.5f;
    o1.x = (acc[4] * inv + b1.x) * 0.5f;
    o1.y = (acc[5] * inv + b1.y) * 0.5f;
    o1.z = (acc[6] * inv + b1.z) * 0.5f;
    o1.w = (acc[7] * inv + b1.w) * 0.5f;
    *(float4*)(out + (size_t)node * CDIM + c8) = o0;
    *(float4*)(out + (size_t)node * CDIM + c8 + 4) = o1;
}

extern "C" void kernel_launch(void* const* d_in, const int* in_sizes, int n_in,
                              void* d_out, int out_size, void* d_ws, size_t ws_size,
                              hipStream_t stream) {
    const float* x       = (const float*)d_in[0];
    const int*   ei      = (const int*)d_in[1];
    const float* W       = (const float*)d_in[2];
    const float* att_src = (const float*)d_in[3];
    const float* att_dst = (const float*)d_in[4];
    const float* bias    = (const float*)d_in[5];
    float* out = (float*)d_out;

    const int N = in_sizes[0] / CDIM;
    const int E = in_sizes[1] / 2;
    const int nb = (N + 255) / 256;

    char* wsb = (char*)d_ws;
    unsigned short* xlh = (unsigned short*)wsb;         wsb += (size_t)N * CDIM * sizeof(unsigned short);
    float* a_src = (float*)wsb;                         wsb += (size_t)N * HEADS * sizeof(float);
    float* a_dst = (float*)wsb;                         wsb += (size_t)N * HEADS * sizeof(float);
    int* counts  = (int*)wsb;                           wsb += (size_t)N * sizeof(int);
    int* cursor  = (int*)wsb;                           wsb += sizeof(int);   // contiguous with counts for one memset
    int* offsets = (int*)wsb;                           wsb += (size_t)N * sizeof(int);
    int* rank    = (int*)wsb;                           wsb += (size_t)E * sizeof(int);
    int* bucket  = (int*)wsb;                           wsb += (size_t)E * sizeof(int);

    hipMemsetAsync(counts, 0, ((size_t)N + 1) * sizeof(int), stream);   // counts + cursor

    const int gemmBlocks = (N + 63) / 64;
    const int histBlocks = (E + 255) / 256;
    gemm_hist_kernel<<<gemmBlocks + histBlocks, 256, 0, stream>>>(
        x, W, att_src, att_dst, xlh, a_src, a_dst, N, ei, ei + E, counts, rank, E, gemmBlocks);
    scan_fused_kernel<<<nb, 256, 0, stream>>>(counts, offsets, cursor, N);
    scatter_kernel<<<(E + 255) / 256, 256, 0, stream>>>(ei, ei + E, offsets, rank, bucket, E);
    gather_kernel<<<(N + 15) / 16, 256, 0, stream>>>(offsets, counts, bucket, xlh, a_src, a_dst, bias, out, N);
}

// Round 11
// 181.171 us; speedup vs baseline: 1.1451x; 1.0712x over previous
//
#include <hip/hip_runtime.h>
#include <math.h>

#define CDIM 128
#define HEADS 4
#define NEG 0.2f

typedef __attribute__((ext_vector_type(8))) short bf16x8;
typedef __attribute__((ext_vector_type(8))) unsigned short u16x8;
typedef __attribute__((ext_vector_type(4))) float f32x4;

static __device__ __forceinline__ unsigned short f2bf(float f) {
    unsigned u = __float_as_uint(f);
    u += 0x7FFFu + ((u >> 16) & 1u);   // round-to-nearest-even
    return (unsigned short)(u >> 16);
}
static __device__ __forceinline__ float bf2f(unsigned short s) {
    return __uint_as_float((unsigned)s << 16);
}

#define LDS_STRIDE 136   // 128 + 8 bf16 pad

// ---------------- tiny precursor: WT[c][k] = bf16(W[k][c]), 32 KB global ----------------
__global__ __launch_bounds__(256) void wt_kernel(const float* __restrict__ W,
                                                 unsigned short* __restrict__ WT) {
    int f = blockIdx.x * 256 + threadIdx.x;       // 4096 total
    int k = f >> 5, c4 = (f & 31) * 4;
    float4 v = *(const float4*)(W + (size_t)k * CDIM + c4);
    WT[(size_t)(c4 + 0) * CDIM + k] = f2bf(v.x);
    WT[(size_t)(c4 + 1) * CDIM + k] = f2bf(v.y);
    WT[(size_t)(c4 + 2) * CDIM + k] = f2bf(v.z);
    WT[(size_t)(c4 + 3) * CDIM + k] = f2bf(v.w);
}

// ---------------- fused: MFMA GEMM (+logits, bf16 out)  ∥  edge histogram+rank ----------------
// B fragments read directly from global WT (L1-resident 32 KB) — no Bs LDS, no transpose scatter.
__global__ __launch_bounds__(256) void gemm_hist_kernel(const float* __restrict__ x,
                                                        const unsigned short* __restrict__ WT,
                                                        const float* __restrict__ att_src,
                                                        const float* __restrict__ att_dst,
                                                        unsigned short* __restrict__ xlh,
                                                        float* __restrict__ a_src,
                                                        float* __restrict__ a_dst, int N,
                                                        const int* __restrict__ esrc,
                                                        const int* __restrict__ edst,
                                                        int* __restrict__ counts,
                                                        int* __restrict__ rank, int E,
                                                        int gemmBlocks) {
    __shared__ unsigned short As[64 * LDS_STRIDE];   // 17.4 KB only

    if (blockIdx.x >= gemmBlocks) {
        // ---- histogram branch ----
        int e = (blockIdx.x - gemmBlocks) * 256 + threadIdx.x;
        if (e < E) {
            int s = esrc[e], d = edst[e];
            if (s != d) rank[e] = atomicAdd(&counts[d], 1);
        }
        return;
    }

    // ---- gemm branch ----
    const int tid = threadIdx.x;
    const int row0 = blockIdx.x * 64;

#pragma unroll
    for (int i = 0; i < 8; ++i) {
        int f = tid + i * 256;
        int r = f >> 5, k4 = f & 31;
        float4 v = make_float4(0.f, 0.f, 0.f, 0.f);
        int gr = row0 + r;
        if (gr < N) v = *(const float4*)(x + (size_t)gr * CDIM + k4 * 4);
        ushort4 h;
        h.x = f2bf(v.x); h.y = f2bf(v.y); h.z = f2bf(v.z); h.w = f2bf(v.w);
        *(ushort4*)(&As[r * LDS_STRIDE + k4 * 4]) = h;
    }
    __syncthreads();

    const int wave = tid >> 6;
    const int lane = tid & 63;
    const int m    = lane & 15;
    const int quad = lane >> 4;
    const int wrow = wave * 16;

    bf16x8 a[4];
#pragma unroll
    for (int ks = 0; ks < 4; ++ks)
        a[ks] = *(const bf16x8*)(&As[(wrow + m) * LDS_STRIDE + ks * 32 + quad * 8]);

    f32x4 acc[8];
#pragma unroll
    for (int t = 0; t < 8; ++t) {
        f32x4 c = {0.f, 0.f, 0.f, 0.f};
#pragma unroll
        for (int ks = 0; ks < 4; ++ks) {
            bf16x8 b = *(const bf16x8*)(WT + (size_t)(t * 16 + m) * CDIM + ks * 32 + quad * 8);
            c = __builtin_amdgcn_mfma_f32_16x16x32_bf16(a[ks], b, c, 0, 0, 0);
        }
        acc[t] = c;
    }

#pragma unroll
    for (int t = 0; t < 8; ++t) {
#pragma unroll
        for (int reg = 0; reg < 4; ++reg) {
            int row = row0 + wrow + quad * 4 + reg;
            if (row < N) xlh[(size_t)row * CDIM + t * 16 + m] = f2bf(acc[t][reg]);
        }
    }

    float ps[4][4], pd[4][4];
#pragma unroll
    for (int h = 0; h < 4; ++h)
#pragma unroll
        for (int reg = 0; reg < 4; ++reg) { ps[h][reg] = 0.f; pd[h][reg] = 0.f; }
#pragma unroll
    for (int t = 0; t < 8; ++t) {
        int h = t >> 1;
        float vs = att_src[t * 16 + m];
        float vd = att_dst[t * 16 + m];
#pragma unroll
        for (int reg = 0; reg < 4; ++reg) {
            ps[h][reg] += acc[t][reg] * vs;
            pd[h][reg] += acc[t][reg] * vd;
        }
    }
#pragma unroll
    for (int off = 8; off > 0; off >>= 1) {
#pragma unroll
        for (int h = 0; h < 4; ++h)
#pragma unroll
            for (int reg = 0; reg < 4; ++reg) {
                ps[h][reg] += __shfl_down(ps[h][reg], off, 16);
                pd[h][reg] += __shfl_down(pd[h][reg], off, 16);
            }
    }
    if (m == 0) {
#pragma unroll
        for (int reg = 0; reg < 4; ++reg) {
            int row = row0 + wrow + quad * 4 + reg;
            if (row < N) {
#pragma unroll
                for (int h = 0; h < 4; ++h) {
                    a_src[row * 4 + h] = ps[h][reg];
                    a_dst[row * 4 + h] = pd[h][reg];
                }
            }
        }
    }
}

// ---------------- single-pass scan: block-local exclusive scan + atomic block base ----------------
__global__ __launch_bounds__(256) void scan_fused_kernel(const int* __restrict__ counts,
                                                         int* __restrict__ offsets,
                                                         int* __restrict__ cursor, int N) {
    __shared__ int sh[256];
    __shared__ int baseSh;
    int idx = blockIdx.x * 256 + threadIdx.x;
    int t = threadIdx.x;
    int c = (idx < N) ? counts[idx] : 0;
    sh[t] = c;
    __syncthreads();
    for (int off = 1; off < 256; off <<= 1) {
        int v = (t >= off) ? sh[t - off] : 0;
        __syncthreads();
        sh[t] += v;
        __syncthreads();
    }
    if (t == 255) baseSh = atomicAdd(cursor, sh[255]);
    __syncthreads();
    if (idx < N) offsets[idx] = baseSh + sh[t] - c;
}

// pure scatter: no atomics
__global__ __launch_bounds__(256) void scatter_kernel(const int* __restrict__ src,
                                                      const int* __restrict__ dst,
                                                      const int* __restrict__ offsets,
                                                      const int* __restrict__ rank,
                                                      int* __restrict__ bucket, int E) {
    int e = blockIdx.x * 256 + threadIdx.x;
    if (e >= E) return;
    int s = src[e], d = dst[e];
    if (s == d) return;
    bucket[offsets[d] + rank[e]] = s;
}

// ---------------- gather: 16 lanes/node (ushort8), one node/group, 8x unrolled ----------------
__global__ __launch_bounds__(256) void gather_kernel(const int* __restrict__ offsets,
                                                     const int* __restrict__ counts,
                                                     const int* __restrict__ bucket,
                                                     const unsigned short* __restrict__ xlh,
                                                     const float* __restrict__ a_src,
                                                     const float* __restrict__ a_dst,
                                                     const float* __restrict__ bias,
                                                     float* __restrict__ out, int N) {
    const int node = blockIdx.x * 16 + (threadIdx.x >> 4);
    const int lane16 = threadIdx.x & 15;
    if (node >= N) return;
    const int c8 = lane16 * 8;
    const int h = lane16 >> 2;

    const float ad = a_dst[node * 4 + h];
    const int beg = offsets[node];
    const int cnt = counts[node];

    float acc[8];
#pragma unroll
    for (int i = 0; i < 8; ++i) acc[i] = 0.f;
    float den = 0.f;

    int j = 0;
    for (; j + 8 <= cnt; j += 8) {
        int s[8];
#pragma unroll
        for (int q = 0; q < 8; ++q) s[q] = bucket[beg + j + q];
        float e[8];
#pragma unroll
        for (int q = 0; q < 8; ++q) e[q] = a_src[s[q] * 4 + h] + ad;
        u16x8 u[8];
#pragma unroll
        for (int q = 0; q < 8; ++q) u[q] = *(const u16x8*)(xlh + (size_t)s[q] * CDIM + c8);
        float w[8];
#pragma unroll
        for (int q = 0; q < 8; ++q) {
            float eq = e[q] > 0.f ? e[q] : NEG * e[q];
            w[q] = __expf(eq);
        }
#pragma unroll
        for (int q = 0; q < 8; ++q) {
#pragma unroll
            for (int i = 0; i < 8; ++i) acc[i] += w[q] * bf2f(u[q][i]);
            den += w[q];
        }
    }
    for (; j < cnt; ++j) {
        int s = bucket[beg + j];
        float e = a_src[s * 4 + h] + ad;
        u16x8 u = *(const u16x8*)(xlh + (size_t)s * CDIM + c8);
        e = e > 0.f ? e : NEG * e;
        float w = __expf(e);
#pragma unroll
        for (int i = 0; i < 8; ++i) acc[i] += w * bf2f(u[i]);
        den += w;
    }
    // self loop
    float es = a_src[node * 4 + h] + ad;
    es = es > 0.f ? es : NEG * es;
    float ws = __expf(es);
    u16x8 u = *(const u16x8*)(xlh + (size_t)node * CDIM + c8);
#pragma unroll
    for (int i = 0; i < 8; ++i) acc[i] += ws * bf2f(u[i]);
    den += ws;

    float inv = 1.0f / den;
    float4 b0 = *(const float4*)(bias + c8);
    float4 b1 = *(const float4*)(bias + c8 + 4);
    float4 o0, o1;
    o0.x = (acc[0] * inv + b0.x) * 0.5f;
    o0.y = (acc[1] * inv + b0.y) * 0.5f;
    o0.z = (acc[2] * inv + b0.z) * 0.5f;
    o0.w = (acc[3] * inv + b0.w) * 0.5f;
    o1.x = (acc[4] * inv + b1.x) * 0.5f;
    o1.y = (acc[5] * inv + b1.y) * 0.5f;
    o1.z = (acc[6] * inv + b1.z) * 0.5f;
    o1.w = (acc[7] * inv + b1.w) * 0.5f;
    *(float4*)(out + (size_t)node * CDIM + c8) = o0;
    *(float4*)(out + (size_t)node * CDIM + c8 + 4) = o1;
}

extern "C" void kernel_launch(void* const* d_in, const int* in_sizes, int n_in,
                              void* d_out, int out_size, void* d_ws, size_t ws_size,
                              hipStream_t stream) {
    const float* x       = (const float*)d_in[0];
    const int*   ei      = (const int*)d_in[1];
    const float* W       = (const float*)d_in[2];
    const float* att_src = (const float*)d_in[3];
    const float* att_dst = (const float*)d_in[4];
    const float* bias    = (const float*)d_in[5];
    float* out = (float*)d_out;

    const int N = in_sizes[0] / CDIM;
    const int E = in_sizes[1] / 2;
    const int nb = (N + 255) / 256;

    char* wsb = (char*)d_ws;
    unsigned short* xlh = (unsigned short*)wsb;         wsb += (size_t)N * CDIM * sizeof(unsigned short);
    unsigned short* WT  = (unsigned short*)wsb;         wsb += (size_t)CDIM * CDIM * sizeof(unsigned short);
    float* a_src = (float*)wsb;                         wsb += (size_t)N * HEADS * sizeof(float);
    float* a_dst = (float*)wsb;                         wsb += (size_t)N * HEADS * sizeof(float);
    int* counts  = (int*)wsb;                           wsb += (size_t)N * sizeof(int);
    int* cursor  = (int*)wsb;                           wsb += sizeof(int);   // contiguous with counts: one memset
    int* offsets = (int*)wsb;                           wsb += (size_t)N * sizeof(int);
    int* rank    = (int*)wsb;                           wsb += (size_t)E * sizeof(int);
    int* bucket  = (int*)wsb;                           wsb += (size_t)E * sizeof(int);

    hipMemsetAsync(counts, 0, ((size_t)N + 1) * sizeof(int), stream);   // counts + cursor

    wt_kernel<<<16, 256, 0, stream>>>(W, WT);
    const int gemmBlocks = (N + 63) / 64;
    const int histBlocks = (E + 255) / 256;
    gemm_hist_kernel<<<gemmBlocks + histBlocks, 256, 0, stream>>>(
        x, WT, att_src, att_dst, xlh, a_src, a_dst, N, ei, ei + E, counts, rank, E, gemmBlocks);
    scan_fused_kernel<<<nb, 256, 0, stream>>>(counts, offsets, cursor, N);
    scatter_kernel<<<(E + 255) / 256, 256, 0, stream>>>(ei, ei + E, offsets, rank, bucket, E);
    gather_kernel<<<(N + 15) / 16, 256, 0, stream>>>(offsets, counts, bucket, xlh, a_src, a_dst, bias, out, N);
}